// Round 3
// baseline (71.019 us; speedup 1.0000x reference)
//
#include <hip/hip_runtime.h>
#include <hip/hip_bf16.h>
#include <stdint.h>

#define N_ROWS 4096
#define D_DIM  256
#define TWO_N  8192
#define ROWB   512                       // bytes per bf16 row
#define C_EXP  2.8853900817779268f       // (2/T)*log2(e) with T=0.5 -> 4*log2e/2... = 2*log2(e)*2? no: sim=2*dot, exp(sim)=2^(dot*2*log2e)

typedef __attribute__((ext_vector_type(8))) short short8;
typedef __attribute__((ext_vector_type(16))) float f32x16;

#define GLOBAL_AS __attribute__((address_space(1)))
#define LDS_AS    __attribute__((address_space(3)))

__device__ __forceinline__ unsigned bf16rne(float f) {
    unsigned u = __float_as_uint(f);
    return (u + 0x7fffu + ((u >> 16) & 1u)) >> 16;
}
__device__ __forceinline__ float bf16val(unsigned bits) {
    return __uint_as_float(bits << 16);
}

// ---------- K1: normalize -> bf16 reps, exact pos-pair sims, bf16 self-dot exp, zero rowsum ----------
__global__ __launch_bounds__(256) void kprep(const float* __restrict__ zi,
                                             const float* __restrict__ zj,
                                             unsigned short* __restrict__ reps,
                                             float* __restrict__ pos,
                                             float* __restrict__ selfexp,
                                             float* __restrict__ rowsum) {
    int wave = threadIdx.x >> 6, lane = threadIdx.x & 63;
    int k = blockIdx.x * 4 + wave;   // 0..4095
    float4 a = *(const float4*)(zi + (size_t)k * D_DIM + lane * 4);
    float4 b = *(const float4*)(zj + (size_t)k * D_DIM + lane * 4);
    float dii = a.x * a.x + a.y * a.y + a.z * a.z + a.w * a.w;
    float djj = b.x * b.x + b.y * b.y + b.z * b.z + b.w * b.w;
    float dij = a.x * b.x + a.y * b.y + a.z * b.z + a.w * b.w;
#pragma unroll
    for (int m = 1; m < 64; m <<= 1) {
        dii += __shfl_xor(dii, m, 64);
        djj += __shfl_xor(djj, m, 64);
        dij += __shfl_xor(dij, m, 64);
    }
    float si = 1.0f / fmaxf(sqrtf(dii), 1e-12f);
    float sj = 1.0f / fmaxf(sqrtf(djj), 1e-12f);

    unsigned a0 = bf16rne(a.x * si), a1 = bf16rne(a.y * si);
    unsigned a2 = bf16rne(a.z * si), a3 = bf16rne(a.w * si);
    unsigned b0 = bf16rne(b.x * sj), b1 = bf16rne(b.y * sj);
    unsigned b2 = bf16rne(b.z * sj), b3 = bf16rne(b.w * sj);
    {
        uint2 o; o.x = a0 | (a1 << 16); o.y = a2 | (a3 << 16);
        *(uint2*)(reps + (size_t)k * D_DIM + lane * 4) = o;
    }
    {
        uint2 o; o.x = b0 | (b1 << 16); o.y = b2 | (b3 << 16);
        *(uint2*)(reps + (size_t)(k + N_ROWS) * D_DIM + lane * 4) = o;
    }
    // self-dots of the ROUNDED bf16 vectors (what the MFMA diagonal computes)
    float fa0 = bf16val(a0), fa1 = bf16val(a1), fa2 = bf16val(a2), fa3 = bf16val(a3);
    float fb0 = bf16val(b0), fb1 = bf16val(b1), fb2 = bf16val(b2), fb3 = bf16val(b3);
    float sa = fa0 * fa0 + fa1 * fa1 + fa2 * fa2 + fa3 * fa3;
    float sb = fb0 * fb0 + fb1 * fb1 + fb2 * fb2 + fb3 * fb3;
#pragma unroll
    for (int m = 1; m < 64; m <<= 1) {
        sa += __shfl_xor(sa, m, 64);
        sb += __shfl_xor(sb, m, 64);
    }
    if (lane == 0) {
        float p = dij * si * sj * 2.0f;   // /TEMPERATURE
        pos[k] = p;
        pos[k + N_ROWS] = p;
        selfexp[k] = __builtin_amdgcn_exp2f(sa * C_EXP);
        selfexp[k + N_ROWS] = __builtin_amdgcn_exp2f(sb * C_EXP);
    }
    if (threadIdx.x < 8) rowsum[blockIdx.x * 8 + threadIdx.x] = 0.0f;
}

// ---------- K2: fused sim GEMM (32x32x16, M-blocked x2) + exp row-sums ----------
// grid 512: rt = bid>>4 (32 row-tiles of BM=256), cs = bid&15 (512 cols each, 8 tiles of 64).
// 4 waves x 64 rows (2 A-frags). Double-buffered LDS, counted vmcnt, raw barriers.
#define STAGE(BUFOFF, COLBASE) do {                                              \
    _Pragma("unroll")                                                            \
    for (int i_ = 0; i_ < 8; ++i_) {                                             \
        int c_ = wave * 8 + i_;                                                  \
        int row_ = 2 * c_ + lhi;                                                 \
        int gs_ = l31 ^ (row_ & 7);                                              \
        const char* ga_ = repsb + (size_t)((COLBASE) + row_) * ROWB + gs_ * 16;  \
        __builtin_amdgcn_global_load_lds((const GLOBAL_AS void*)ga_,             \
            (LDS_AS void*)(lds + (BUFOFF) + c_ * 1024), 16, 0, 0);               \
    }                                                                            \
} while (0)

__global__ __launch_bounds__(256, 2) void kmain(const unsigned short* __restrict__ reps,
                                                float* __restrict__ rowsum) {
    __shared__ __align__(16) char lds[2 * 32768];

    const int rt = blockIdx.x >> 4;
    const int cs = blockIdx.x & 15;
    const int tid = threadIdx.x;
    const int wave = tid >> 6, lane = tid & 63;
    const int l31 = lane & 31, lhi = lane >> 5, x7 = l31 & 7;
    const int rowbase = rt * 256 + wave * 64;
    const char* repsb = (const char*)reps;
    const int col0 = cs * 512;

    STAGE(0, col0);                       // prefetch tile 0 (oldest vmem ops)

    // A fragments: 2 row-frags x 16 k-steps, full K in registers
    short8 afrag[2][16];
#pragma unroll
    for (int rf = 0; rf < 2; ++rf) {
        const char* ar = repsb + (size_t)(rowbase + rf * 32 + l31) * ROWB + lhi * 16;
#pragma unroll
        for (int ks = 0; ks < 16; ++ks)
            afrag[rf][ks] = *(const short8*)(ar + ks * 32);
    }

    float sumexp[2][16];
#pragma unroll
    for (int rf = 0; rf < 2; ++rf)
#pragma unroll
        for (int r = 0; r < 16; ++r) sumexp[rf][r] = 0.0f;

#pragma unroll 2
    for (int t = 0; t < 8; ++t) {
        const int buf = (t & 1) << 15;
        if (t < 7) {
            STAGE(((t + 1) & 1) << 15, col0 + (t + 1) * 64);
            asm volatile("s_waitcnt vmcnt(8)" ::: "memory");   // tile t landed; t+1 in flight
        } else {
            asm volatile("s_waitcnt vmcnt(0)" ::: "memory");   // drain at last tile
        }
        __builtin_amdgcn_s_barrier();
        __builtin_amdgcn_sched_barrier(0);

        f32x16 acc00, acc01, acc10, acc11;
#pragma unroll
        for (int r = 0; r < 16; ++r) { acc00[r] = 0.f; acc01[r] = 0.f; acc10[r] = 0.f; acc11[r] = 0.f; }

#pragma unroll
        for (int ks = 0; ks < 16; ++ks) {
            int ds = ((2 * ks + lhi) ^ x7) << 4;
            short8 b0 = *(const short8*)(lds + buf + l31 * ROWB + ds);
            short8 b1 = *(const short8*)(lds + buf + (32 + l31) * ROWB + ds);
            acc00 = __builtin_amdgcn_mfma_f32_32x32x16_bf16(afrag[0][ks], b0, acc00, 0, 0, 0);
            acc01 = __builtin_amdgcn_mfma_f32_32x32x16_bf16(afrag[0][ks], b1, acc01, 0, 0, 0);
            acc10 = __builtin_amdgcn_mfma_f32_32x32x16_bf16(afrag[1][ks], b0, acc10, 0, 0, 0);
            acc11 = __builtin_amdgcn_mfma_f32_32x32x16_bf16(afrag[1][ks], b1, acc11, 0, 0, 0);
        }
        __builtin_amdgcn_sched_barrier(0);
        __builtin_amdgcn_s_barrier();     // all reads of buf done before tile t+2 writes land

        // epilogue after barrier2: overlaps other waves' staging
#pragma unroll
        for (int r = 0; r < 16; ++r) {
            sumexp[0][r] += __builtin_amdgcn_exp2f(acc00[r] * C_EXP)
                          + __builtin_amdgcn_exp2f(acc01[r] * C_EXP);
            sumexp[1][r] += __builtin_amdgcn_exp2f(acc10[r] * C_EXP)
                          + __builtin_amdgcn_exp2f(acc11[r] * C_EXP);
        }
    }

    // reduce across 32 lanes sharing each row; one atomic per row
#pragma unroll
    for (int rf = 0; rf < 2; ++rf)
#pragma unroll
        for (int r = 0; r < 16; ++r) {
            float s = sumexp[rf][r];
            s += __shfl_xor(s, 1, 64);
            s += __shfl_xor(s, 2, 64);
            s += __shfl_xor(s, 4, 64);
            s += __shfl_xor(s, 8, 64);
            s += __shfl_xor(s, 16, 64);
            if (l31 == 0)
                atomicAdd(&rowsum[rowbase + rf * 32 + (r & 3) + 8 * (r >> 2) + 4 * lhi], s);
        }
}

// ---------- K3: loss = mean(log(rowsum - selfexp) - pos) ----------
__global__ __launch_bounds__(1024) void kfinal(const float* __restrict__ rowsum,
                                               const float* __restrict__ pos,
                                               const float* __restrict__ selfexp,
                                               float* __restrict__ out) {
    __shared__ float red[16];
    float local = 0.0f;
    for (int r = threadIdx.x; r < TWO_N; r += 1024)
        local += __builtin_amdgcn_logf(rowsum[r] - selfexp[r]) * 0.6931471805599453f - pos[r];
#pragma unroll
    for (int m = 1; m < 64; m <<= 1) local += __shfl_xor(local, m, 64);
    if ((threadIdx.x & 63) == 0) red[threadIdx.x >> 6] = local;
    __syncthreads();
    if (threadIdx.x == 0) {
        float t = 0.0f;
#pragma unroll
        for (int i = 0; i < 16; ++i) t += red[i];
        out[0] = t * (1.0f / (float)TWO_N);
    }
}

extern "C" void kernel_launch(void* const* d_in, const int* in_sizes, int n_in,
                              void* d_out, int out_size, void* d_ws, size_t ws_size,
                              hipStream_t stream) {
    const float* zi = (const float*)d_in[0];
    const float* zj = (const float*)d_in[1];
    float* out = (float*)d_out;

    unsigned short* reps = (unsigned short*)d_ws;                       // 4 MiB
    float* rowsum = (float*)((char*)d_ws + (size_t)TWO_N * D_DIM * 2);  // 32 KiB
    float* pos = rowsum + TWO_N;                                        // 32 KiB
    float* selfexp = pos + TWO_N;                                       // 32 KiB

    kprep<<<1024, 256, 0, stream>>>(zi, zj, reps, pos, selfexp, rowsum);
    kmain<<<512, 256, 0, stream>>>(reps, rowsum);
    kfinal<<<1, 1024, 0, stream>>>(rowsum, pos, selfexp, out);
}

// Round 4
// 70.994 us; speedup vs baseline: 1.0004x; 1.0004x over previous
//
#include <hip/hip_runtime.h>
#include <hip/hip_bf16.h>
#include <stdint.h>

#define N_ROWS 4096
#define D_DIM  256
#define TWO_N  8192
#define ROWB   512                       // bytes per bf16 row
#define C_EXP  2.8853900817779268f       // 2*log2(e): exp(sim)=exp(2*dot)=2^(dot*2*log2e)

typedef __attribute__((ext_vector_type(8))) short short8;
typedef __attribute__((ext_vector_type(16))) float f32x16;

#define GLOBAL_AS __attribute__((address_space(1)))
#define LDS_AS    __attribute__((address_space(3)))

__device__ __forceinline__ unsigned bf16rne(float f) {
    unsigned u = __float_as_uint(f);
    return (u + 0x7fffu + ((u >> 16) & 1u)) >> 16;
}
__device__ __forceinline__ float bf16val(unsigned bits) {
    return __uint_as_float(bits << 16);
}

// ---------- K1: normalize -> bf16 reps, exact pos-pair sims, bf16 self-dot exp, zero rowsum ----------
__global__ __launch_bounds__(256) void kprep(const float* __restrict__ zi,
                                             const float* __restrict__ zj,
                                             unsigned short* __restrict__ reps,
                                             float* __restrict__ pos,
                                             float* __restrict__ selfexp,
                                             float* __restrict__ rowsum) {
    int wave = threadIdx.x >> 6, lane = threadIdx.x & 63;
    int k = blockIdx.x * 4 + wave;   // 0..4095
    float4 a = *(const float4*)(zi + (size_t)k * D_DIM + lane * 4);
    float4 b = *(const float4*)(zj + (size_t)k * D_DIM + lane * 4);
    float dii = a.x * a.x + a.y * a.y + a.z * a.z + a.w * a.w;
    float djj = b.x * b.x + b.y * b.y + b.z * b.z + b.w * b.w;
    float dij = a.x * b.x + a.y * b.y + a.z * b.z + a.w * b.w;
#pragma unroll
    for (int m = 1; m < 64; m <<= 1) {
        dii += __shfl_xor(dii, m, 64);
        djj += __shfl_xor(djj, m, 64);
        dij += __shfl_xor(dij, m, 64);
    }
    float si = 1.0f / fmaxf(sqrtf(dii), 1e-12f);
    float sj = 1.0f / fmaxf(sqrtf(djj), 1e-12f);

    unsigned a0 = bf16rne(a.x * si), a1 = bf16rne(a.y * si);
    unsigned a2 = bf16rne(a.z * si), a3 = bf16rne(a.w * si);
    unsigned b0 = bf16rne(b.x * sj), b1 = bf16rne(b.y * sj);
    unsigned b2 = bf16rne(b.z * sj), b3 = bf16rne(b.w * sj);
    {
        uint2 o; o.x = a0 | (a1 << 16); o.y = a2 | (a3 << 16);
        *(uint2*)(reps + (size_t)k * D_DIM + lane * 4) = o;
    }
    {
        uint2 o; o.x = b0 | (b1 << 16); o.y = b2 | (b3 << 16);
        *(uint2*)(reps + (size_t)(k + N_ROWS) * D_DIM + lane * 4) = o;
    }
    float fa0 = bf16val(a0), fa1 = bf16val(a1), fa2 = bf16val(a2), fa3 = bf16val(a3);
    float fb0 = bf16val(b0), fb1 = bf16val(b1), fb2 = bf16val(b2), fb3 = bf16val(b3);
    float sa = fa0 * fa0 + fa1 * fa1 + fa2 * fa2 + fa3 * fa3;
    float sb = fb0 * fb0 + fb1 * fb1 + fb2 * fb2 + fb3 * fb3;
#pragma unroll
    for (int m = 1; m < 64; m <<= 1) {
        sa += __shfl_xor(sa, m, 64);
        sb += __shfl_xor(sb, m, 64);
    }
    if (lane == 0) {
        float p = dij * si * sj * 2.0f;   // /TEMPERATURE
        pos[k] = p;
        pos[k + N_ROWS] = p;
        selfexp[k] = __builtin_amdgcn_exp2f(sa * C_EXP);
        selfexp[k + N_ROWS] = __builtin_amdgcn_exp2f(sb * C_EXP);
    }
    if (threadIdx.x < 8) rowsum[blockIdx.x * 8 + threadIdx.x] = 0.0f;
}

// ---------- K2: symmetric-triangle fused sim GEMM + exp row/col sums ----------
// 2080 blocks = upper-triangle (rt<=ct) of 64x64 tiles of 128x128. 4 waves x 32 rows.
// A: full K=256 in regs (64 VGPR). B: 64col x 128K tiles (16KB) double-buffered via
// global_load_lds (linear dest, inverse-swizzled source, swizzled read).
// Off-diag tiles accumulate BOTH row-partials and (by symmetry) col-partials.
#define STAGE(BUFOFF, CF, KC) do {                                                   \
    _Pragma("unroll")                                                                \
    for (int i_ = 0; i_ < 4; ++i_) {                                                 \
        int c_ = wave * 4 + i_;               /* chunk 0..15, 1KB each */            \
        int col_ = c_ * 4 + (lane >> 4);      /* 0..63 within tile */                \
        int gs_ = (lane & 15) ^ (col_ & 7);   /* inverse-swizzled 16B slot */        \
        const char* ga_ = repsb + (size_t)(colbase + (CF) * 64 + col_) * ROWB        \
                          + (KC) * 256 + gs_ * 16;                                   \
        __builtin_amdgcn_global_load_lds((const GLOBAL_AS void*)ga_,                 \
            (LDS_AS void*)(lds + (BUFOFF) + c_ * 1024), 16, 0, 0);                   \
    }                                                                                \
} while (0)

__global__ __launch_bounds__(256, 3) void kmain(const unsigned short* __restrict__ reps,
                                                float* __restrict__ rowsum) {
    __shared__ __align__(16) char lds[2 * 16384 + 2048];
    float* colpart = (float*)(lds + 32768);   // [4 waves][128 cols]

    const int tid = threadIdx.x;
    const int wave = tid >> 6, lane = tid & 63;
    const int l31 = lane & 31, lhi = lane >> 5, x7 = l31 & 7;

    // XCD swizzle (2080 = 8*260, bijective) + triangular decode
    int i = (blockIdx.x & 7) * 260 + (blockIdx.x >> 3);
    int rt = (int)((129.0f - sqrtf(16641.0f - 8.0f * (float)i)) * 0.5f);
    while ((rt + 1) * (129 - (rt + 1)) / 2 <= i) ++rt;
    while (rt * (129 - rt) / 2 > i) --rt;
    const int ct = rt + (i - rt * (129 - rt) / 2);
    const bool diag = (rt == ct);

    const int rowbase = rt * 128 + wave * 32;
    const int colbase = ct * 128;
    const char* repsb = (const char*)reps;

    STAGE(0, 0, 0);                      // prefetch tile 0 (oldest vmem ops)

    // A fragments: 32 rows, full K=256 (16 k-steps of 16), 64 VGPRs
    short8 afrag[16];
    {
        const char* ar = repsb + (size_t)(rowbase + l31) * ROWB + lhi * 16;
#pragma unroll
        for (int ks = 0; ks < 16; ++ks)
            afrag[ks] = *(const short8*)(ar + ks * 32);
    }

    float rsum[16];
#pragma unroll
    for (int r = 0; r < 16; ++r) rsum[r] = 0.0f;
    float csum[2][2];

#pragma unroll
    for (int cf = 0; cf < 2; ++cf) {
        f32x16 acc0, acc1;
#pragma unroll
        for (int r = 0; r < 16; ++r) { acc0[r] = 0.0f; acc1[r] = 0.0f; }

#pragma unroll
        for (int kc = 0; kc < 2; ++kc) {
            const int s = cf * 2 + kc;
            const int buf = (s & 1) << 14;
            if (s < 3) {
                const int s1 = s + 1;
                STAGE((s1 & 1) << 14, s1 >> 1, s1 & 1);
                if (s == 0) { asm volatile("s_waitcnt vmcnt(12)" ::: "memory"); }
                else        { asm volatile("s_waitcnt vmcnt(4)"  ::: "memory"); }
            } else {
                asm volatile("s_waitcnt vmcnt(0)" ::: "memory");
            }
            __builtin_amdgcn_s_barrier();       // stage-s data visible to all waves
            __builtin_amdgcn_sched_barrier(0);

#pragma unroll
            for (int ks = 0; ks < 8; ++ks) {
                int ds = ((2 * ks + lhi) ^ x7) << 4;
                short8 b0 = *(const short8*)(lds + buf + l31 * 256 + ds);
                short8 b1 = *(const short8*)(lds + buf + (32 + l31) * 256 + ds);
                acc0 = __builtin_amdgcn_mfma_f32_32x32x16_bf16(afrag[kc * 8 + ks], b0, acc0, 0, 0, 0);
                acc1 = __builtin_amdgcn_mfma_f32_32x32x16_bf16(afrag[kc * 8 + ks], b1, acc1, 0, 0, 0);
            }
            __builtin_amdgcn_sched_barrier(0);
            __builtin_amdgcn_s_barrier();       // reads done before next stage overwrites
        }

        // epilogue for this 64-col tile: exp once, feed row-partials and col-partials
        float c0 = 0.0f, c1 = 0.0f;
#pragma unroll
        for (int r = 0; r < 16; ++r) {
            float e0 = __builtin_amdgcn_exp2f(acc0[r] * C_EXP);
            float e1 = __builtin_amdgcn_exp2f(acc1[r] * C_EXP);
            rsum[r] += e0 + e1;
            c0 += e0;
            c1 += e1;
        }
        csum[cf][0] = c0;
        csum[cf][1] = c1;
    }

    // row-partials: reduce 32 lanes sharing each row, one atomic per row
#pragma unroll
    for (int r = 0; r < 16; ++r) {
        float s = rsum[r];
        s += __shfl_xor(s, 1, 64);
        s += __shfl_xor(s, 2, 64);
        s += __shfl_xor(s, 4, 64);
        s += __shfl_xor(s, 8, 64);
        s += __shfl_xor(s, 16, 64);
        if (l31 == 0)
            atomicAdd(&rowsum[rowbase + (r & 3) + 8 * (r >> 2) + 4 * lhi], s);
    }

    // col-partials (symmetry): only off-diagonal blocks; cross-wave reduce in LDS
    if (!diag) {
#pragma unroll
        for (int cf = 0; cf < 2; ++cf)
#pragma unroll
            for (int f = 0; f < 2; ++f) {
                float v = csum[cf][f];
                v += __shfl_xor(v, 32, 64);
                if (lhi == 0) colpart[wave * 128 + cf * 64 + f * 32 + l31] = v;
            }
        __syncthreads();
        if (tid < 128) {
            float v = colpart[tid] + colpart[128 + tid] + colpart[256 + tid] + colpart[384 + tid];
            atomicAdd(&rowsum[colbase + tid], v);
        }
    }
}

// ---------- K3: loss = mean(log(rowsum - selfexp) - pos) ----------
__global__ __launch_bounds__(1024) void kfinal(const float* __restrict__ rowsum,
                                               const float* __restrict__ pos,
                                               const float* __restrict__ selfexp,
                                               float* __restrict__ out) {
    __shared__ float red[16];
    float local = 0.0f;
    for (int r = threadIdx.x; r < TWO_N; r += 1024)
        local += __builtin_amdgcn_logf(rowsum[r] - selfexp[r]) * 0.6931471805599453f - pos[r];
#pragma unroll
    for (int m = 1; m < 64; m <<= 1) local += __shfl_xor(local, m, 64);
    if ((threadIdx.x & 63) == 0) red[threadIdx.x >> 6] = local;
    __syncthreads();
    if (threadIdx.x == 0) {
        float t = 0.0f;
#pragma unroll
        for (int i = 0; i < 16; ++i) t += red[i];
        out[0] = t * (1.0f / (float)TWO_N);
    }
}

extern "C" void kernel_launch(void* const* d_in, const int* in_sizes, int n_in,
                              void* d_out, int out_size, void* d_ws, size_t ws_size,
                              hipStream_t stream) {
    const float* zi = (const float*)d_in[0];
    const float* zj = (const float*)d_in[1];
    float* out = (float*)d_out;

    unsigned short* reps = (unsigned short*)d_ws;                       // 4 MiB
    float* rowsum = (float*)((char*)d_ws + (size_t)TWO_N * D_DIM * 2);  // 32 KiB
    float* pos = rowsum + TWO_N;                                        // 32 KiB
    float* selfexp = pos + TWO_N;                                       // 32 KiB

    kprep<<<1024, 256, 0, stream>>>(zi, zj, reps, pos, selfexp, rowsum);
    kmain<<<2080, 256, 0, stream>>>(reps, rowsum);
    kfinal<<<1, 1024, 0, stream>>>(rowsum, pos, selfexp, out);
}